// Round 3
// baseline (57.559 us; speedup 1.0000x reference)
//
#include <hip/hip_runtime.h>

#define BB 16
#define LQ 64
#define LK 256
#define EM 128
#define NH 8
#define DKK 16
#define DIM 48
#define NHID 128

// ws layout (float offsets)
#define QP_OFF 0
#define KP_OFF (BB*LQ*EM)                    // 131072 floats
#define XX_OFF (KP_OFF + BB*LK*EM)           // 655360

// ---------------- Kernel 1: Q/K projections -----------------
// 640 blocks x 128 thr; 8 rows/block. rows<1024: query@Wq^T+bq -> qp, else key -> kp.
__global__ __launch_bounds__(128) void proj_kernel(
    const float* __restrict__ query, const float* __restrict__ key,
    const float* __restrict__ Wq, const float* __restrict__ bq,
    const float* __restrict__ Wk, const float* __restrict__ bk,
    float* __restrict__ ws)
{
    __shared__ __align__(16) float sX[8][EM];
    int row0 = blockIdx.x * 8;
    int t = threadIdx.x;
    const float* X; const float* W; const float* bias; float* out; int base;
    if (row0 < BB * LQ) { X = query; W = Wq; bias = bq; out = ws + QP_OFF; base = row0; }
    else                { X = key;   W = Wk; bias = bk; out = ws + KP_OFF; base = row0 - BB * LQ; }

    {
        const float4* src = (const float4*)(X + (size_t)base * EM);
        float4* dst = (float4*)(&sX[0][0]);
        dst[t] = src[t];
        dst[t + 128] = src[t + 128];
    }
    __syncthreads();

    float acc[8];
    #pragma unroll
    for (int r = 0; r < 8; r++) acc[r] = 0.f;

    const float4* w4 = (const float4*)(W + (size_t)t * EM);
    #pragma unroll 8
    for (int k4 = 0; k4 < EM / 4; k4++) {
        float4 w = w4[k4];
        #pragma unroll
        for (int r = 0; r < 8; r++) {
            float4 x = ((const float4*)sX[r])[k4];
            acc[r] += x.x * w.x + x.y * w.y + x.z * w.z + x.w * w.w;
        }
    }
    float bb = bias[t];
    #pragma unroll
    for (int r = 0; r < 8; r++) out[(size_t)(base + r) * EM + t] = acc[r] + bb;
}

// ---------------- Kernel 2: attention v3 -----------------
// grid = B*H*4 = 512 blocks (2/CU), 256 threads, LDS ~31KB.
// Per 64-k chunk:
//   phase1: thread (kr=t&63, qg=t>>6): scores for k-row kr x 4 q -> e -> sE[kr][qg*4]
//   stage : masked V (cols 0..47) | mask-as-float (cols 48..95) -> sW[64][100]
//   PV    : thread (kl=t&7, qb=(t>>3)&3, jg=t>>5): acc[4q][12j] += e4 * w12
//           (4 LDS b128 per 48 fmac; W-reads are 64-distinct dense reads)
// End: 3-step halving shfl butterfly over kl; Z (jg>=4) -> LDS; num lanes divide+store.
__global__ __launch_bounds__(256) void attn_kernel(
    const float* __restrict__ qp, const float* __restrict__ kp,
    const float* __restrict__ value, const int* __restrict__ mask,
    float* __restrict__ xx)
{
    __shared__ __align__(16) float sQ[16][DKK];   // 1 KB
    __shared__ __align__(16) float sE[64][20];    // 5 KB   (80B row stride)
    __shared__ __align__(16) float sW[64][100];   // 25.6 KB (400B row stride)

    int bid = blockIdx.x;
    int b  = bid >> 5;
    int h  = (bid >> 2) & 7;
    int q0 = (bid & 3) * 16;
    int t  = threadIdx.x;

    if (t < 64) {
        int r = t >> 2, u = t & 3;
        *(float4*)&sQ[r][u * 4] =
            *(const float4*)(qp + (size_t)(b * LQ + q0 + r) * EM + h * DKK + u * 4);
    }

    int kr = t & 63;
    int qg = t >> 6;
    int kl = t & 7;
    int qb = (t >> 3) & 3;
    int jg = t >> 5;

    float acc[4][12];
    #pragma unroll
    for (int qi = 0; qi < 4; ++qi)
        #pragma unroll
        for (int j = 0; j < 12; ++j) acc[qi][j] = 0.f;

    const float* vb = value + (size_t)b * LK * DIM;
    const int*   mb = mask  + (size_t)b * LK * DIM;

    __syncthreads();   // sQ ready

    for (int c = 0; c < 4; ++c) {
        int kc = c * 64;
        // phase 1: scores + exp
        {
            const float4* krow = (const float4*)(kp + (size_t)(b * LK + kc + kr) * EM + h * DKK);
            float4 k0 = krow[0], k1 = krow[1], k2 = krow[2], k3 = krow[3];
            float4 ev;
            float* evp = (float*)&ev;
            #pragma unroll
            for (int qi = 0; qi < 4; ++qi) {
                const float4* qrow = (const float4*)sQ[qg * 4 + qi];
                float4 a = qrow[0], b2 = qrow[1], c2 = qrow[2], d2 = qrow[3];
                float s = k0.x*a.x + k0.y*a.y + k0.z*a.z + k0.w*a.w
                        + k1.x*b2.x + k1.y*b2.y + k1.z*b2.z + k1.w*b2.w
                        + k2.x*c2.x + k2.y*c2.y + k2.z*c2.z + k2.w*c2.w
                        + k3.x*d2.x + k3.y*d2.y + k3.z*d2.z + k3.w*d2.w;
                evp[qi] = __expf(s * 0.25f);
            }
            *(float4*)&sE[kr][qg * 4] = ev;
        }
        // stage masked V + mask floats (1536 f4 slots, 6 per thread)
        #pragma unroll
        for (int u = 0; u < 6; ++u) {
            int f = t + 256 * u;
            int r = f / 24, cs = f - r * 24;
            float4 o;
            if (cs < 12) {
                float4 v = *(const float4*)(vb + (size_t)(kc + r) * DIM + cs * 4);
                int4  m  = *(const int4*)  (mb + (size_t)(kc + r) * DIM + cs * 4);
                o.x = m.x ? v.x : 0.f; o.y = m.y ? v.y : 0.f;
                o.z = m.z ? v.z : 0.f; o.w = m.w ? v.w : 0.f;
            } else {
                int4 m = *(const int4*)(mb + (size_t)(kc + r) * DIM + (cs - 12) * 4);
                o.x = m.x ? 1.f : 0.f; o.y = m.y ? 1.f : 0.f;
                o.z = m.z ? 1.f : 0.f; o.w = m.w ? 1.f : 0.f;
            }
            *(float4*)&sW[r][cs * 4] = o;
        }
        __syncthreads();
        // PV
        #pragma unroll
        for (int i = 0; i < 8; ++i) {
            int k = kl + 8 * i;
            float4 e4 = *(const float4*)&sE[k][qb * 4];
            const float4* wr = (const float4*)&sW[k][jg * 12];
            float4 w0 = wr[0], w1 = wr[1], w2 = wr[2];
            float* ep = (float*)&e4;
            #pragma unroll
            for (int qi = 0; qi < 4; ++qi) {
                float e = ep[qi];
                acc[qi][0]  += e * w0.x; acc[qi][1]  += e * w0.y;
                acc[qi][2]  += e * w0.z; acc[qi][3]  += e * w0.w;
                acc[qi][4]  += e * w1.x; acc[qi][5]  += e * w1.y;
                acc[qi][6]  += e * w1.z; acc[qi][7]  += e * w1.w;
                acc[qi][8]  += e * w2.x; acc[qi][9]  += e * w2.y;
                acc[qi][10] += e * w2.z; acc[qi][11] += e * w2.w;
            }
        }
        __syncthreads();
    }

    // ---- reduce over kl (halving butterfly, static indexing throughout) ----
    float v48[48];
    #pragma unroll
    for (int qi = 0; qi < 4; ++qi)
        #pragma unroll
        for (int j = 0; j < 12; ++j) v48[qi * 12 + j] = acc[qi][j];

    bool hi1 = (kl & 1) != 0;
    float s1[24];
    #pragma unroll
    for (int i = 0; i < 24; ++i) {
        float keep = hi1 ? v48[24 + i] : v48[i];
        float send = hi1 ? v48[i] : v48[24 + i];
        s1[i] = keep + __shfl_xor(send, 1, 64);
    }
    bool hi2 = (kl & 2) != 0;
    float s2[12];
    #pragma unroll
    for (int i = 0; i < 12; ++i) {
        float keep = hi2 ? s1[12 + i] : s1[i];
        float send = hi2 ? s1[i] : s1[12 + i];
        s2[i] = keep + __shfl_xor(send, 2, 64);
    }
    bool hi3 = (kl & 4) != 0;
    float s3[6];
    #pragma unroll
    for (int i = 0; i < 6; ++i) {
        float keep = hi3 ? s2[6 + i] : s2[i];
        float send = hi3 ? s2[i] : s2[6 + i];
        s3[i] = keep + __shfl_xor(send, 4, 64);
    }

    int base = (hi1 ? 24 : 0) + (hi2 ? 12 : 0) + (hi3 ? 6 : 0);
    int qi = base / 12;        // 0..3 (base%12 in {0,6} -> single q per thread)
    int j0 = base - qi * 12;   // 0 or 6
    int q  = qb * 4 + qi;

    float* sZ = &sE[0][0];     // reuse: 16 x 52 floats
    if (jg >= 4) {
        int jz = (jg - 4) * 12 + j0;
        #pragma unroll
        for (int i = 0; i < 6; ++i) sZ[q * 52 + jz + i] = s3[i];
    }
    __syncthreads();
    if (jg < 4) {
        int j = jg * 12 + j0;
        float* xr = xx + (size_t)(b * LQ + q0 + q) * (NH * DIM) + h * DIM + j;
        #pragma unroll
        for (int i = 0; i < 6; ++i) xr[i] = s3[i] / sZ[q * 52 + j + i];
    }
}

// ---------------- Kernel 3: out = x @ Wo^T + bo -----------------
__global__ __launch_bounds__(128) void outproj_kernel(
    const float* __restrict__ x, const float* __restrict__ Wo,
    const float* __restrict__ bo, float* __restrict__ out)
{
    __shared__ __align__(16) float sX[4][NH * DIM];
    int row0 = blockIdx.x * 4;
    int t = threadIdx.x;
    {
        const float4* src = (const float4*)(x + (size_t)row0 * (NH * DIM));
        float4* dst = (float4*)(&sX[0][0]);
        #pragma unroll
        for (int u = 0; u < 3; u++) dst[t + u * 128] = src[t + u * 128];
    }
    __syncthreads();

    float acc[4] = {0.f, 0.f, 0.f, 0.f};
    const float4* w4 = (const float4*)(Wo + (size_t)t * (NH * DIM));
    #pragma unroll 8
    for (int k4 = 0; k4 < (NH * DIM) / 4; k4++) {
        float4 w = w4[k4];
        #pragma unroll
        for (int r = 0; r < 4; r++) {
            float4 xv = ((const float4*)sX[r])[k4];
            acc[r] += xv.x * w.x + xv.y * w.y + xv.z * w.z + xv.w * w.w;
        }
    }
    float bb = bo[t];
    #pragma unroll
    for (int r = 0; r < 4; r++) out[(size_t)(row0 + r) * NHID + t] = acc[r] + bb;
}

extern "C" void kernel_launch(void* const* d_in, const int* in_sizes, int n_in,
                              void* d_out, int out_size, void* d_ws, size_t ws_size,
                              hipStream_t stream) {
    const float* query = (const float*)d_in[0];
    const float* key   = (const float*)d_in[1];
    const float* value = (const float*)d_in[2];
    const int*   mask  = (const int*)  d_in[3];
    const float* Wq    = (const float*)d_in[4];
    const float* bq    = (const float*)d_in[5];
    const float* Wk    = (const float*)d_in[6];
    const float* bk    = (const float*)d_in[7];
    const float* Wo    = (const float*)d_in[8];
    const float* bo    = (const float*)d_in[9];
    float* out = (float*)d_out;
    float* ws = (float*)d_ws;

    proj_kernel<<<dim3((BB*LQ + BB*LK) / 8), dim3(128), 0, stream>>>(
        query, key, Wq, bq, Wk, bk, ws);
    attn_kernel<<<dim3(BB * NH * 4), dim3(256), 0, stream>>>(
        ws + QP_OFF, ws + KP_OFF, value, mask, ws + XX_OFF);
    outproj_kernel<<<dim3(BB * LQ / 4), dim3(128), 0, stream>>>(
        ws + XX_OFF, Wo, bo, out);
}

// Round 4
// 46.676 us; speedup vs baseline: 1.2332x; 1.2332x over previous
//
#include <hip/hip_runtime.h>

#define BB 16
#define LQ 64
#define LK 256
#define EM 128
#define NH 8
#define DKK 16
#define DIM 48
#define NHID 128

// ws layout (float offsets)
#define QP_OFF 0
#define KP_OFF (BB*LQ*EM)                    // 131072 floats
#define XX_OFF (KP_OFF + BB*LK*EM)           // 655360

// ---------------- Kernel 1: Q/K projections -----------------
__global__ __launch_bounds__(128) void proj_kernel(
    const float* __restrict__ query, const float* __restrict__ key,
    const float* __restrict__ Wq, const float* __restrict__ bq,
    const float* __restrict__ Wk, const float* __restrict__ bk,
    float* __restrict__ ws)
{
    __shared__ __align__(16) float sX[8][EM];
    int row0 = blockIdx.x * 8;
    int t = threadIdx.x;
    const float* X; const float* W; const float* bias; float* out; int base;
    if (row0 < BB * LQ) { X = query; W = Wq; bias = bq; out = ws + QP_OFF; base = row0; }
    else                { X = key;   W = Wk; bias = bk; out = ws + KP_OFF; base = row0 - BB * LQ; }

    {
        const float4* src = (const float4*)(X + (size_t)base * EM);
        float4* dst = (float4*)(&sX[0][0]);
        dst[t] = src[t];
        dst[t + 128] = src[t + 128];
    }
    __syncthreads();

    float acc[8];
    #pragma unroll
    for (int r = 0; r < 8; r++) acc[r] = 0.f;

    const float4* w4 = (const float4*)(W + (size_t)t * EM);
    #pragma unroll 8
    for (int k4 = 0; k4 < EM / 4; k4++) {
        float4 w = w4[k4];
        #pragma unroll
        for (int r = 0; r < 8; r++) {
            float4 x = ((const float4*)sX[r])[k4];
            acc[r] += x.x * w.x + x.y * w.y + x.z * w.z + x.w * w.w;
        }
    }
    float bb = bias[t];
    #pragma unroll
    for (int r = 0; r < 8; r++) out[(size_t)(base + r) * EM + t] = acc[r] + bb;
}

// ---------------- Kernel 2: attention v4 -----------------
// grid = B*H*4 = 512 blocks, 256 threads, LDS ~31.6KB.
// T14 async staging: V/mask for chunk c+1 prefetched into regs during PV of c.
// Stage map: thread covers sW row (t>>2), f4 slots (t&3)+4u (u<3: V*m; +12: m-float),
// mask int4 regs reused for both -> 6 global loads, 6 LDS writes, zero div/mod.
__global__ __launch_bounds__(256) void attn_kernel(
    const float* __restrict__ qp, const float* __restrict__ kp,
    const float* __restrict__ value, const int* __restrict__ mask,
    float* __restrict__ xx)
{
    __shared__ __align__(16) float sQ[16][DKK];   // 1 KB
    __shared__ __align__(16) float sE[64][20];    // 5 KB
    __shared__ __align__(16) float sW[64][100];   // 25.6 KB

    int bid = blockIdx.x;
    int b  = bid >> 5;
    int h  = (bid >> 2) & 7;
    int q0 = (bid & 3) * 16;
    int t  = threadIdx.x;

    int kr = t & 63;
    int qg = t >> 6;
    int kl = t & 7;
    int qb = (t >> 3) & 3;
    int jg = t >> 5;
    int sr = t >> 2;            // stage row 0..63
    int sc = t & 3;             // stage lane-in-row

    const float* vb = value + (size_t)b * LK * DIM;
    const int*   mb = mask  + (size_t)b * LK * DIM;

    // prefetch chunk 0 V/mask into regs
    float4 pv0, pv1, pv2; int4 pm0, pm1, pm2;
    {
        const float* vr = vb + (size_t)sr * DIM + sc * 4;
        const int*   mr = mb + (size_t)sr * DIM + sc * 4;
        pv0 = *(const float4*)(vr);      pm0 = *(const int4*)(mr);
        pv1 = *(const float4*)(vr + 16); pm1 = *(const int4*)(mr + 16);
        pv2 = *(const float4*)(vr + 32); pm2 = *(const int4*)(mr + 32);
    }

    if (t < 64) {
        int r = t >> 2, u = t & 3;
        *(float4*)&sQ[r][u * 4] =
            *(const float4*)(qp + (size_t)(b * LQ + q0 + r) * EM + h * DKK + u * 4);
    }

    float acc[4][12];
    #pragma unroll
    for (int qi = 0; qi < 4; ++qi)
        #pragma unroll
        for (int j = 0; j < 12; ++j) acc[qi][j] = 0.f;

    __syncthreads();   // sQ ready

    for (int c = 0; c < 4; ++c) {
        int kc = c * 64;
        // ---- stage from prefetched regs ----
        {
            float4 vm, mf;
            vm.x = pm0.x ? pv0.x : 0.f; vm.y = pm0.y ? pv0.y : 0.f;
            vm.z = pm0.z ? pv0.z : 0.f; vm.w = pm0.w ? pv0.w : 0.f;
            mf.x = pm0.x ? 1.f : 0.f;   mf.y = pm0.y ? 1.f : 0.f;
            mf.z = pm0.z ? 1.f : 0.f;   mf.w = pm0.w ? 1.f : 0.f;
            *(float4*)&sW[sr][sc * 4]        = vm;
            *(float4*)&sW[sr][(sc + 12) * 4] = mf;
            vm.x = pm1.x ? pv1.x : 0.f; vm.y = pm1.y ? pv1.y : 0.f;
            vm.z = pm1.z ? pv1.z : 0.f; vm.w = pm1.w ? pv1.w : 0.f;
            mf.x = pm1.x ? 1.f : 0.f;   mf.y = pm1.y ? 1.f : 0.f;
            mf.z = pm1.z ? 1.f : 0.f;   mf.w = pm1.w ? 1.f : 0.f;
            *(float4*)&sW[sr][(sc + 4) * 4]  = vm;
            *(float4*)&sW[sr][(sc + 16) * 4] = mf;
            vm.x = pm2.x ? pv2.x : 0.f; vm.y = pm2.y ? pv2.y : 0.f;
            vm.z = pm2.z ? pv2.z : 0.f; vm.w = pm2.w ? pv2.w : 0.f;
            mf.x = pm2.x ? 1.f : 0.f;   mf.y = pm2.y ? 1.f : 0.f;
            mf.z = pm2.z ? 1.f : 0.f;   mf.w = pm2.w ? 1.f : 0.f;
            *(float4*)&sW[sr][(sc + 8) * 4]  = vm;
            *(float4*)&sW[sr][(sc + 20) * 4] = mf;
        }
        // ---- scores + exp for k-row kc+kr, 4 q's ----
        {
            const float4* krow = (const float4*)(kp + (size_t)(b * LK + kc + kr) * EM + h * DKK);
            float4 k0 = krow[0], k1 = krow[1], k2 = krow[2], k3 = krow[3];
            float4 ev;
            float* evp = (float*)&ev;
            #pragma unroll
            for (int qi = 0; qi < 4; ++qi) {
                const float4* qrow = (const float4*)sQ[qg * 4 + qi];
                float4 a = qrow[0], b2 = qrow[1], c2 = qrow[2], d2 = qrow[3];
                float s = k0.x*a.x + k0.y*a.y + k0.z*a.z + k0.w*a.w
                        + k1.x*b2.x + k1.y*b2.y + k1.z*b2.z + k1.w*b2.w
                        + k2.x*c2.x + k2.y*c2.y + k2.z*c2.z + k2.w*c2.w
                        + k3.x*d2.x + k3.y*d2.y + k3.z*d2.z + k3.w*d2.w;
                evp[qi] = __expf(s * 0.25f);
            }
            *(float4*)&sE[kr][qg * 4] = ev;
        }
        __syncthreads();
        // ---- prefetch next chunk V/mask (hidden under PV) ----
        if (c < 3) {
            const float* vr = vb + (size_t)(kc + 64 + sr) * DIM + sc * 4;
            const int*   mr = mb + (size_t)(kc + 64 + sr) * DIM + sc * 4;
            pv0 = *(const float4*)(vr);      pm0 = *(const int4*)(mr);
            pv1 = *(const float4*)(vr + 16); pm1 = *(const int4*)(mr + 16);
            pv2 = *(const float4*)(vr + 32); pm2 = *(const int4*)(mr + 32);
        }
        // ---- PV ----
        #pragma unroll
        for (int i = 0; i < 8; ++i) {
            int k = kl + 8 * i;
            float4 e4 = *(const float4*)&sE[k][qb * 4];
            const float4* wr = (const float4*)&sW[k][jg * 12];
            float4 w0 = wr[0], w1 = wr[1], w2 = wr[2];
            float* ep = (float*)&e4;
            #pragma unroll
            for (int qi = 0; qi < 4; ++qi) {
                float e = ep[qi];
                acc[qi][0]  += e * w0.x; acc[qi][1]  += e * w0.y;
                acc[qi][2]  += e * w0.z; acc[qi][3]  += e * w0.w;
                acc[qi][4]  += e * w1.x; acc[qi][5]  += e * w1.y;
                acc[qi][6]  += e * w1.z; acc[qi][7]  += e * w1.w;
                acc[qi][8]  += e * w2.x; acc[qi][9]  += e * w2.y;
                acc[qi][10] += e * w2.z; acc[qi][11] += e * w2.w;
            }
        }
        __syncthreads();
    }

    // ---- reduce over kl (halving butterfly, static indexing) ----
    float v48[48];
    #pragma unroll
    for (int qi = 0; qi < 4; ++qi)
        #pragma unroll
        for (int j = 0; j < 12; ++j) v48[qi * 12 + j] = acc[qi][j];

    bool hi1 = (kl & 1) != 0;
    float s1[24];
    #pragma unroll
    for (int i = 0; i < 24; ++i) {
        float keep = hi1 ? v48[24 + i] : v48[i];
        float send = hi1 ? v48[i] : v48[24 + i];
        s1[i] = keep + __shfl_xor(send, 1, 64);
    }
    bool hi2 = (kl & 2) != 0;
    float s2[12];
    #pragma unroll
    for (int i = 0; i < 12; ++i) {
        float keep = hi2 ? s1[12 + i] : s1[i];
        float send = hi2 ? s1[i] : s1[12 + i];
        s2[i] = keep + __shfl_xor(send, 2, 64);
    }
    bool hi3 = (kl & 4) != 0;
    float s3[6];
    #pragma unroll
    for (int i = 0; i < 6; ++i) {
        float keep = hi3 ? s2[6 + i] : s2[i];
        float send = hi3 ? s2[i] : s2[6 + i];
        s3[i] = keep + __shfl_xor(send, 4, 64);
    }

    int base = (hi1 ? 24 : 0) + (hi2 ? 12 : 0) + (hi3 ? 6 : 0);
    int qi = base / 12;
    int j0 = base - qi * 12;
    int q  = qb * 4 + qi;

    float* sZ = &sE[0][0];     // reuse: 16 x 52 floats
    if (jg >= 4) {
        int jz = (jg - 4) * 12 + j0;
        #pragma unroll
        for (int i = 0; i < 6; ++i) sZ[q * 52 + jz + i] = s3[i];
    }
    __syncthreads();
    if (jg < 4) {
        int j = jg * 12 + j0;
        float* xr = xx + (size_t)(b * LQ + q0 + q) * (NH * DIM) + h * DIM + j;
        #pragma unroll
        for (int i = 0; i < 6; ++i) xr[i] = s3[i] / sZ[q * 52 + j + i];
    }
}

// ---------------- Kernel 3: out = x @ Wo^T + bo -----------------
__global__ __launch_bounds__(128) void outproj_kernel(
    const float* __restrict__ x, const float* __restrict__ Wo,
    const float* __restrict__ bo, float* __restrict__ out)
{
    __shared__ __align__(16) float sX[4][NH * DIM];
    int row0 = blockIdx.x * 4;
    int t = threadIdx.x;
    {
        const float4* src = (const float4*)(x + (size_t)row0 * (NH * DIM));
        float4* dst = (float4*)(&sX[0][0]);
        #pragma unroll
        for (int u = 0; u < 3; u++) dst[t + u * 128] = src[t + u * 128];
    }
    __syncthreads();

    float acc[4] = {0.f, 0.f, 0.f, 0.f};
    const float4* w4 = (const float4*)(Wo + (size_t)t * (NH * DIM));
    #pragma unroll 8
    for (int k4 = 0; k4 < (NH * DIM) / 4; k4++) {
        float4 w = w4[k4];
        #pragma unroll
        for (int r = 0; r < 4; r++) {
            float4 xv = ((const float4*)sX[r])[k4];
            acc[r] += xv.x * w.x + xv.y * w.y + xv.z * w.z + xv.w * w.w;
        }
    }
    float bb = bo[t];
    #pragma unroll
    for (int r = 0; r < 4; r++) out[(size_t)(row0 + r) * NHID + t] = acc[r] + bb;
}

extern "C" void kernel_launch(void* const* d_in, const int* in_sizes, int n_in,
                              void* d_out, int out_size, void* d_ws, size_t ws_size,
                              hipStream_t stream) {
    const float* query = (const float*)d_in[0];
    const float* key   = (const float*)d_in[1];
    const float* value = (const float*)d_in[2];
    const int*   mask  = (const int*)  d_in[3];
    const float* Wq    = (const float*)d_in[4];
    const float* bq    = (const float*)d_in[5];
    const float* Wk    = (const float*)d_in[6];
    const float* bk    = (const float*)d_in[7];
    const float* Wo    = (const float*)d_in[8];
    const float* bo    = (const float*)d_in[9];
    float* out = (float*)d_out;
    float* ws = (float*)d_ws;

    proj_kernel<<<dim3((BB*LQ + BB*LK) / 8), dim3(128), 0, stream>>>(
        query, key, Wq, bq, Wk, bk, ws);
    attn_kernel<<<dim3(BB * NH * 4), dim3(256), 0, stream>>>(
        ws + QP_OFF, ws + KP_OFF, value, mask, ws + XX_OFF);
    outproj_kernel<<<dim3(BB * LQ / 4), dim3(128), 0, stream>>>(
        ws + XX_OFF, Wo, bo, out);
}

// Round 5
// 42.972 us; speedup vs baseline: 1.3395x; 1.0862x over previous
//
#include <hip/hip_runtime.h>

#define BB 16
#define LQ 64
#define LK 256
#define EM 128
#define NH 8
#define DKK 16
#define DIM 48
#define NHID 128

// ws layout (float offsets)
#define QP_OFF 0
#define KP_OFF (BB*LQ*EM)                    // 131072 floats
#define XX_OFF (KP_OFF + BB*LK*EM)           // 655360

// ---------------- Kernel 1: Q/K projections (LDS-free, scalar-uniform X) ----
// 640 blocks x 128 thr; 8 rows/block. Thread t owns output column t (W row t
// in VGPRs); the 8 input-row values are block-uniform -> s_load + SGPR-operand
// v_fmac. No LDS, no barrier.
__global__ __launch_bounds__(128) void proj_kernel(
    const float* __restrict__ query, const float* __restrict__ key,
    const float* __restrict__ Wq, const float* __restrict__ bq,
    const float* __restrict__ Wk, const float* __restrict__ bk,
    float* __restrict__ ws)
{
    int row0 = blockIdx.x * 8;
    int t = threadIdx.x;
    const float* X; const float* W; const float* bias; float* out; int base;
    if (row0 < BB * LQ) { X = query; W = Wq; bias = bq; out = ws + QP_OFF; base = row0; }
    else                { X = key;   W = Wk; bias = bk; out = ws + KP_OFF; base = row0 - BB * LQ; }

    float acc[8];
    #pragma unroll
    for (int r = 0; r < 8; r++) acc[r] = 0.f;

    const float4* w4 = (const float4*)(W + (size_t)t * EM);
    const float4* x4 = (const float4*)(X + (size_t)base * EM);   // block-uniform

    #pragma unroll 4
    for (int k4 = 0; k4 < EM / 4; k4++) {
        float4 w = w4[k4];
        #pragma unroll
        for (int r = 0; r < 8; r++) {
            float4 x = x4[r * (EM / 4) + k4];      // uniform address -> s_load
            acc[r] += x.x * w.x + x.y * w.y + x.z * w.z + x.w * w.w;
        }
    }
    float bb = bias[t];
    #pragma unroll
    for (int r = 0; r < 8; r++) out[(size_t)(base + r) * EM + t] = acc[r] + bb;
}

// ---------------- Kernel 2: attention v4 (unchanged from round 4) -----------
__global__ __launch_bounds__(256) void attn_kernel(
    const float* __restrict__ qp, const float* __restrict__ kp,
    const float* __restrict__ value, const int* __restrict__ mask,
    float* __restrict__ xx)
{
    __shared__ __align__(16) float sQ[16][DKK];   // 1 KB
    __shared__ __align__(16) float sE[64][20];    // 5 KB
    __shared__ __align__(16) float sW[64][100];   // 25.6 KB

    int bid = blockIdx.x;
    int b  = bid >> 5;
    int h  = (bid >> 2) & 7;
    int q0 = (bid & 3) * 16;
    int t  = threadIdx.x;

    int kr = t & 63;
    int qg = t >> 6;
    int kl = t & 7;
    int qb = (t >> 3) & 3;
    int jg = t >> 5;
    int sr = t >> 2;            // stage row 0..63
    int sc = t & 3;             // stage lane-in-row

    const float* vb = value + (size_t)b * LK * DIM;
    const int*   mb = mask  + (size_t)b * LK * DIM;

    // prefetch chunk 0 V/mask into regs
    float4 pv0, pv1, pv2; int4 pm0, pm1, pm2;
    {
        const float* vr = vb + (size_t)sr * DIM + sc * 4;
        const int*   mr = mb + (size_t)sr * DIM + sc * 4;
        pv0 = *(const float4*)(vr);      pm0 = *(const int4*)(mr);
        pv1 = *(const float4*)(vr + 16); pm1 = *(const int4*)(mr + 16);
        pv2 = *(const float4*)(vr + 32); pm2 = *(const int4*)(mr + 32);
    }

    if (t < 64) {
        int r = t >> 2, u = t & 3;
        *(float4*)&sQ[r][u * 4] =
            *(const float4*)(qp + (size_t)(b * LQ + q0 + r) * EM + h * DKK + u * 4);
    }

    float acc[4][12];
    #pragma unroll
    for (int qi = 0; qi < 4; ++qi)
        #pragma unroll
        for (int j = 0; j < 12; ++j) acc[qi][j] = 0.f;

    __syncthreads();   // sQ ready

    for (int c = 0; c < 4; ++c) {
        int kc = c * 64;
        // ---- stage from prefetched regs ----
        {
            float4 vm, mf;
            vm.x = pm0.x ? pv0.x : 0.f; vm.y = pm0.y ? pv0.y : 0.f;
            vm.z = pm0.z ? pv0.z : 0.f; vm.w = pm0.w ? pv0.w : 0.f;
            mf.x = pm0.x ? 1.f : 0.f;   mf.y = pm0.y ? 1.f : 0.f;
            mf.z = pm0.z ? 1.f : 0.f;   mf.w = pm0.w ? 1.f : 0.f;
            *(float4*)&sW[sr][sc * 4]        = vm;
            *(float4*)&sW[sr][(sc + 12) * 4] = mf;
            vm.x = pm1.x ? pv1.x : 0.f; vm.y = pm1.y ? pv1.y : 0.f;
            vm.z = pm1.z ? pv1.z : 0.f; vm.w = pm1.w ? pv1.w : 0.f;
            mf.x = pm1.x ? 1.f : 0.f;   mf.y = pm1.y ? 1.f : 0.f;
            mf.z = pm1.z ? 1.f : 0.f;   mf.w = pm1.w ? 1.f : 0.f;
            *(float4*)&sW[sr][(sc + 4) * 4]  = vm;
            *(float4*)&sW[sr][(sc + 16) * 4] = mf;
            vm.x = pm2.x ? pv2.x : 0.f; vm.y = pm2.y ? pv2.y : 0.f;
            vm.z = pm2.z ? pv2.z : 0.f; vm.w = pm2.w ? pv2.w : 0.f;
            mf.x = pm2.x ? 1.f : 0.f;   mf.y = pm2.y ? 1.f : 0.f;
            mf.z = pm2.z ? 1.f : 0.f;   mf.w = pm2.w ? 1.f : 0.f;
            *(float4*)&sW[sr][(sc + 8) * 4]  = vm;
            *(float4*)&sW[sr][(sc + 20) * 4] = mf;
        }
        // ---- scores + exp for k-row kc+kr, 4 q's ----
        {
            const float4* krow = (const float4*)(kp + (size_t)(b * LK + kc + kr) * EM + h * DKK);
            float4 k0 = krow[0], k1 = krow[1], k2 = krow[2], k3 = krow[3];
            float4 ev;
            float* evp = (float*)&ev;
            #pragma unroll
            for (int qi = 0; qi < 4; ++qi) {
                const float4* qrow = (const float4*)sQ[qg * 4 + qi];
                float4 a = qrow[0], b2 = qrow[1], c2 = qrow[2], d2 = qrow[3];
                float s = k0.x*a.x + k0.y*a.y + k0.z*a.z + k0.w*a.w
                        + k1.x*b2.x + k1.y*b2.y + k1.z*b2.z + k1.w*b2.w
                        + k2.x*c2.x + k2.y*c2.y + k2.z*c2.z + k2.w*c2.w
                        + k3.x*d2.x + k3.y*d2.y + k3.z*d2.z + k3.w*d2.w;
                evp[qi] = __expf(s * 0.25f);
            }
            *(float4*)&sE[kr][qg * 4] = ev;
        }
        __syncthreads();
        // ---- prefetch next chunk V/mask (hidden under PV) ----
        if (c < 3) {
            const float* vr = vb + (size_t)(kc + 64 + sr) * DIM + sc * 4;
            const int*   mr = mb + (size_t)(kc + 64 + sr) * DIM + sc * 4;
            pv0 = *(const float4*)(vr);      pm0 = *(const int4*)(mr);
            pv1 = *(const float4*)(vr + 16); pm1 = *(const int4*)(mr + 16);
            pv2 = *(const float4*)(vr + 32); pm2 = *(const int4*)(mr + 32);
        }
        // ---- PV ----
        #pragma unroll
        for (int i = 0; i < 8; ++i) {
            int k = kl + 8 * i;
            float4 e4 = *(const float4*)&sE[k][qb * 4];
            const float4* wr = (const float4*)&sW[k][jg * 12];
            float4 w0 = wr[0], w1 = wr[1], w2 = wr[2];
            float* ep = (float*)&e4;
            #pragma unroll
            for (int qi = 0; qi < 4; ++qi) {
                float e = ep[qi];
                acc[qi][0]  += e * w0.x; acc[qi][1]  += e * w0.y;
                acc[qi][2]  += e * w0.z; acc[qi][3]  += e * w0.w;
                acc[qi][4]  += e * w1.x; acc[qi][5]  += e * w1.y;
                acc[qi][6]  += e * w1.z; acc[qi][7]  += e * w1.w;
                acc[qi][8]  += e * w2.x; acc[qi][9]  += e * w2.y;
                acc[qi][10] += e * w2.z; acc[qi][11] += e * w2.w;
            }
        }
        __syncthreads();
    }

    // ---- reduce over kl (halving butterfly, static indexing) ----
    float v48[48];
    #pragma unroll
    for (int qi = 0; qi < 4; ++qi)
        #pragma unroll
        for (int j = 0; j < 12; ++j) v48[qi * 12 + j] = acc[qi][j];

    bool hi1 = (kl & 1) != 0;
    float s1[24];
    #pragma unroll
    for (int i = 0; i < 24; ++i) {
        float keep = hi1 ? v48[24 + i] : v48[i];
        float send = hi1 ? v48[i] : v48[24 + i];
        s1[i] = keep + __shfl_xor(send, 1, 64);
    }
    bool hi2 = (kl & 2) != 0;
    float s2[12];
    #pragma unroll
    for (int i = 0; i < 12; ++i) {
        float keep = hi2 ? s1[12 + i] : s1[i];
        float send = hi2 ? s1[i] : s1[12 + i];
        s2[i] = keep + __shfl_xor(send, 2, 64);
    }
    bool hi3 = (kl & 4) != 0;
    float s3[6];
    #pragma unroll
    for (int i = 0; i < 6; ++i) {
        float keep = hi3 ? s2[6 + i] : s2[i];
        float send = hi3 ? s2[i] : s2[6 + i];
        s3[i] = keep + __shfl_xor(send, 4, 64);
    }

    int base = (hi1 ? 24 : 0) + (hi2 ? 12 : 0) + (hi3 ? 6 : 0);
    int qi = base / 12;
    int j0 = base - qi * 12;
    int q  = qb * 4 + qi;

    float* sZ = &sE[0][0];     // reuse: 16 x 52 floats
    if (jg >= 4) {
        int jz = (jg - 4) * 12 + j0;
        #pragma unroll
        for (int i = 0; i < 6; ++i) sZ[q * 52 + jz + i] = s3[i];
    }
    __syncthreads();
    if (jg < 4) {
        int j = jg * 12 + j0;
        float* xr = xx + (size_t)(b * LQ + q0 + q) * (NH * DIM) + h * DIM + j;
        #pragma unroll
        for (int i = 0; i < 6; ++i) xr[i] = s3[i] / sZ[q * 52 + j + i];
    }
}

// ---------------- Kernel 3: out = x @ Wo^T + bo (LDS-free, scalar-uniform x) -
// 256 blocks x 128 thr; 4 rows/block; thread t owns output column t.
__global__ __launch_bounds__(128) void outproj_kernel(
    const float* __restrict__ x, const float* __restrict__ Wo,
    const float* __restrict__ bo, float* __restrict__ out)
{
    int row0 = blockIdx.x * 4;
    int t = threadIdx.x;

    float acc[4] = {0.f, 0.f, 0.f, 0.f};
    const float4* w4 = (const float4*)(Wo + (size_t)t * (NH * DIM));
    const float4* x4 = (const float4*)(x + (size_t)row0 * (NH * DIM));  // uniform

    #pragma unroll 4
    for (int k4 = 0; k4 < (NH * DIM) / 4; k4++) {
        float4 w = w4[k4];
        #pragma unroll
        for (int r = 0; r < 4; r++) {
            float4 xv = x4[r * ((NH * DIM) / 4) + k4];   // uniform -> s_load
            acc[r] += xv.x * w.x + xv.y * w.y + xv.z * w.z + xv.w * w.w;
        }
    }
    float bb = bo[t];
    #pragma unroll
    for (int r = 0; r < 4; r++) out[(size_t)(row0 + r) * NHID + t] = acc[r] + bb;
}

extern "C" void kernel_launch(void* const* d_in, const int* in_sizes, int n_in,
                              void* d_out, int out_size, void* d_ws, size_t ws_size,
                              hipStream_t stream) {
    const float* query = (const float*)d_in[0];
    const float* key   = (const float*)d_in[1];
    const float* value = (const float*)d_in[2];
    const int*   mask  = (const int*)  d_in[3];
    const float* Wq    = (const float*)d_in[4];
    const float* bq    = (const float*)d_in[5];
    const float* Wk    = (const float*)d_in[6];
    const float* bk    = (const float*)d_in[7];
    const float* Wo    = (const float*)d_in[8];
    const float* bo    = (const float*)d_in[9];
    float* out = (float*)d_out;
    float* ws = (float*)d_ws;

    proj_kernel<<<dim3((BB*LQ + BB*LK) / 8), dim3(128), 0, stream>>>(
        query, key, Wq, bq, Wk, bk, ws);
    attn_kernel<<<dim3(BB * NH * 4), dim3(256), 0, stream>>>(
        ws + QP_OFF, ws + KP_OFF, value, mask, ws + XX_OFF);
    outproj_kernel<<<dim3(BB * LQ / 4), dim3(128), 0, stream>>>(
        ws + XX_OFF, Wo, bo, out);
}